// Round 12
// baseline (462.814 us; speedup 1.0000x reference)
//
#include <hip/hip_runtime.h>
#include <hip/hip_bf16.h>

using bf16 = __hip_bfloat16;

#define BATCH 16
#define NNODE 2000
#define DIM   128
#define ODIM  64
#define NLAYER 3
#define BN    (BATCH*NNODE)   // 32000
#define NP1   (NNODE+1)       // 2001
#define CHK   125             // chunks per batch
#define CKS   16              // chunk size (125*16 = 2000)

// converted-input element offsets inside cvt buffer
#define OFF_COORDS 0
#define OFF_EW0    64000
#define OFF_EB0    64256
#define OFF_EW1    64384
#define OFF_EB1    80768
#define OFF_GW     80896
#define OFF_GA1    130048
#define OFF_GA2    130432
#define OFF_PW     130816
#define OFF_PB     139008
#define CVT_TOT    139072

struct InPtrs { const void* p[10]; };

// ------------- convert ALL inputs to fp32 (sniff embedded per block) ---------------
__global__ void convert_all_k(InPtrs in, float* __restrict__ dst, float* __restrict__ flag)
{
    __shared__ int scnt[256];
    const unsigned short* raw = (const unsigned short*)in.p[0];
    int t = threadIdx.x, c = 0;
    for (int k = t; k < 2048; k += 256){
        unsigned short u = raw[2*k];                 // first 8 KB, safe either dtype
        int e = (u >> 7) & 0xFF;
        if (e >= 100 && e <= 140) ++c;
    }
    scnt[t] = c;
    __syncthreads();
    for (int s = 128; s; s >>= 1){ if (t < s) scnt[t] += scnt[t+s]; __syncthreads(); }
    const bool isbf16 = (scnt[0] >= 1800);
    if (blockIdx.x == 0 && t == 0) flag[0] = isbf16 ? 1.0f : 0.0f;

    const int off[11] = {OFF_COORDS,OFF_EW0,OFF_EB0,OFF_EW1,OFF_EB1,
                         OFF_GW,OFF_GA1,OFF_GA2,OFF_PW,OFF_PB,CVT_TOT};
    int i = blockIdx.x*256 + t;
    if (i >= CVT_TOT) return;
    int seg = 0;
    #pragma unroll
    for (int s = 1; s < 10; ++s) if (i >= off[s]) seg = s;
    int li = i - off[seg];
    if (isbf16) dst[i] = __bfloat162float(((const bf16*)in.p[seg])[li]);
    else        dst[i] = ((const float*)in.p[seg])[li];
}

// ------------- fused encoder: h = relu(coords@w0+b0) @ w1 + b1 ---------------------
__global__ __launch_bounds__(256) void encgemm_k(const float* __restrict__ cvt,
                                                 float* __restrict__ out)
{
    __shared__ __align__(16) float sW[128*64];   // [k][cc] 32 KB
    __shared__ __align__(16) float sA[32*128];   // [r][k]  16 KB
    const int rt = blockIdx.x, cb = blockIdx.y, tid = threadIdx.x;
    const float* W      = cvt + OFF_EW1;
    const float* bias   = cvt + OFF_EB1;
    const float* coords = cvt + OFF_COORDS;
    const float* w0     = cvt + OFF_EW0;
    const float* b0v    = cvt + OFF_EB0;

    for (int e = tid; e < 128*64; e += 256){
        int k = e >> 6, cc = e & 63;
        sW[e] = W[k*DIM + cb*64 + cc];
    }
    for (int e = tid; e < 32*128; e += 256){
        int r = e >> 7, k = e & 127;
        int node = rt*32 + r;
        float c0 = coords[node*2+0], c1 = coords[node*2+1];
        float v = fmaf(c0, w0[k], fmaf(c1, w0[DIM+k], b0v[k]));
        sA[e] = v > 0.f ? v : 0.f;
    }
    __syncthreads();

    const int cq = tid & 15, rr = tid >> 4;
    float4 acc0 = make_float4(0.f,0.f,0.f,0.f);
    float4 acc1 = make_float4(0.f,0.f,0.f,0.f);
    for (int kq = 0; kq < 32; ++kq){
        float4 w0q = *(float4*)&sW[(kq*4+0)*64 + cq*4];
        float4 w1q = *(float4*)&sW[(kq*4+1)*64 + cq*4];
        float4 w2q = *(float4*)&sW[(kq*4+2)*64 + cq*4];
        float4 w3q = *(float4*)&sW[(kq*4+3)*64 + cq*4];
        float4 a0 = *(float4*)&sA[rr*128 + kq*4];
        float4 a1 = *(float4*)&sA[(rr+16)*128 + kq*4];
        acc0.x = fmaf(a0.x,w0q.x, fmaf(a0.y,w1q.x, fmaf(a0.z,w2q.x, fmaf(a0.w,w3q.x, acc0.x))));
        acc0.y = fmaf(a0.x,w0q.y, fmaf(a0.y,w1q.y, fmaf(a0.z,w2q.y, fmaf(a0.w,w3q.y, acc0.y))));
        acc0.z = fmaf(a0.x,w0q.z, fmaf(a0.y,w1q.z, fmaf(a0.z,w2q.z, fmaf(a0.w,w3q.z, acc0.z))));
        acc0.w = fmaf(a0.x,w0q.w, fmaf(a0.y,w1q.w, fmaf(a0.z,w2q.w, fmaf(a0.w,w3q.w, acc0.w))));
        acc1.x = fmaf(a1.x,w0q.x, fmaf(a1.y,w1q.x, fmaf(a1.z,w2q.x, fmaf(a1.w,w3q.x, acc1.x))));
        acc1.y = fmaf(a1.x,w0q.y, fmaf(a1.y,w1q.y, fmaf(a1.z,w2q.y, fmaf(a1.w,w3q.y, acc1.y))));
        acc1.z = fmaf(a1.x,w0q.z, fmaf(a1.y,w1q.z, fmaf(a1.z,w2q.z, fmaf(a1.w,w3q.z, acc1.z))));
        acc1.w = fmaf(a1.x,w0q.w, fmaf(a1.y,w1q.w, fmaf(a1.z,w2q.w, fmaf(a1.w,w3q.w, acc1.w))));
    }
    const int col0 = cb*64 + cq*4;
    float b0=bias[col0], b1=bias[col0+1], b2=bias[col0+2], b3=bias[col0+3];
    int r0 = rt*32 + rr;
    *(float4*)&out[(size_t)r0*DIM + col0]      = make_float4(acc0.x+b0, acc0.y+b1, acc0.z+b2, acc0.w+b3);
    *(float4*)&out[(size_t)(r0+16)*DIM + col0] = make_float4(acc1.x+b0, acc1.y+b1, acc1.z+b2, acc1.w+b3);
}

// ------------- GAT GEMM: Wh = h @ W, fused e1/e2 64-col partial dots ---------------
__global__ __launch_bounds__(256) void gatgemm_k(const float* __restrict__ A,
    const float* __restrict__ W, const float* __restrict__ a1, const float* __restrict__ a2,
    float* __restrict__ out, float* __restrict__ e1p, float* __restrict__ e2p)
{
    __shared__ __align__(16) float sW[128*64];
    __shared__ __align__(16) float sA[32*128];
    const int rt = blockIdx.x, cb = blockIdx.y, tid = threadIdx.x;

    for (int e = tid; e < 128*64; e += 256){
        int k = e >> 6, cc = e & 63;
        sW[e] = W[k*DIM + cb*64 + cc];
    }
    const float4* Ab = (const float4*)(A + (size_t)rt*32*128);
    float4* sA4 = (float4*)sA;
    for (int q = tid; q < 32*32; q += 256) sA4[q] = Ab[q];
    __syncthreads();

    const int cq = tid & 15, rr = tid >> 4;
    float4 acc0 = make_float4(0.f,0.f,0.f,0.f);
    float4 acc1 = make_float4(0.f,0.f,0.f,0.f);
    for (int kq = 0; kq < 32; ++kq){
        float4 w0q = *(float4*)&sW[(kq*4+0)*64 + cq*4];
        float4 w1q = *(float4*)&sW[(kq*4+1)*64 + cq*4];
        float4 w2q = *(float4*)&sW[(kq*4+2)*64 + cq*4];
        float4 w3q = *(float4*)&sW[(kq*4+3)*64 + cq*4];
        float4 a0 = *(float4*)&sA[rr*128 + kq*4];
        float4 a1q = *(float4*)&sA[(rr+16)*128 + kq*4];
        acc0.x = fmaf(a0.x,w0q.x, fmaf(a0.y,w1q.x, fmaf(a0.z,w2q.x, fmaf(a0.w,w3q.x, acc0.x))));
        acc0.y = fmaf(a0.x,w0q.y, fmaf(a0.y,w1q.y, fmaf(a0.z,w2q.y, fmaf(a0.w,w3q.y, acc0.y))));
        acc0.z = fmaf(a0.x,w0q.z, fmaf(a0.y,w1q.z, fmaf(a0.z,w2q.z, fmaf(a0.w,w3q.z, acc0.z))));
        acc0.w = fmaf(a0.x,w0q.w, fmaf(a0.y,w1q.w, fmaf(a0.z,w2q.w, fmaf(a0.w,w3q.w, acc0.w))));
        acc1.x = fmaf(a1q.x,w0q.x, fmaf(a1q.y,w1q.x, fmaf(a1q.z,w2q.x, fmaf(a1q.w,w3q.x, acc1.x))));
        acc1.y = fmaf(a1q.x,w0q.y, fmaf(a1q.y,w1q.y, fmaf(a1q.z,w2q.y, fmaf(a1q.w,w3q.y, acc1.y))));
        acc1.z = fmaf(a1q.x,w0q.z, fmaf(a1q.y,w1q.z, fmaf(a1q.z,w2q.z, fmaf(a1q.w,w3q.z, acc1.z))));
        acc1.w = fmaf(a1q.x,w0q.w, fmaf(a1q.y,w1q.w, fmaf(a1q.z,w2q.w, fmaf(a1q.w,w3q.w, acc1.w))));
    }
    const int col0 = cb*64 + cq*4;
    int r0 = rt*32 + rr;
    *(float4*)&out[(size_t)r0*DIM + col0]      = acc0;
    *(float4*)&out[(size_t)(r0+16)*DIM + col0] = acc1;

    float a1v0=a1[col0], a1v1=a1[col0+1], a1v2=a1[col0+2], a1v3=a1[col0+3];
    float a2v0=a2[col0], a2v1=a2[col0+1], a2v2=a2[col0+2], a2v3=a2[col0+3];
    float p1r0 = acc0.x*a1v0 + acc0.y*a1v1 + acc0.z*a1v2 + acc0.w*a1v3;
    float p2r0 = acc0.x*a2v0 + acc0.y*a2v1 + acc0.z*a2v2 + acc0.w*a2v3;
    float p1r1 = acc1.x*a1v0 + acc1.y*a1v1 + acc1.z*a1v2 + acc1.w*a1v3;
    float p2r1 = acc1.x*a2v0 + acc1.y*a2v1 + acc1.z*a2v2 + acc1.w*a2v3;
    #pragma unroll
    for (int msk = 1; msk < 16; msk <<= 1){
        p1r0 += __shfl_xor(p1r0, msk); p2r0 += __shfl_xor(p2r0, msk);
        p1r1 += __shfl_xor(p1r1, msk); p2r1 += __shfl_xor(p2r1, msk);
    }
    if (cq == 0){
        e1p[cb*BN + r0]    = p1r0;  e2p[cb*BN + r0]    = p2r0;
        e1p[cb*BN + r0+16] = p1r1;  e2p[cb*BN + r0+16] = p2r1;
    }
}

// ------------- final projection GEMM, output dtype per flag ------------------------
__global__ __launch_bounds__(256) void gemmout_k(const float* __restrict__ A,
    const float* __restrict__ W, const float* __restrict__ bias,
    void* __restrict__ outp, const float* __restrict__ flag)
{
    __shared__ __align__(16) float sW[128*64];
    __shared__ __align__(16) float sA[32*128];
    const int rt = blockIdx.x, tid = threadIdx.x;
    for (int e = tid; e < 128*64; e += 256){
        int k = e >> 6, cc = e & 63;
        sW[e] = W[k*ODIM + cc];
    }
    const float4* Ab = (const float4*)(A + (size_t)rt*32*128);
    float4* sA4 = (float4*)sA;
    for (int q = tid; q < 32*32; q += 256) sA4[q] = Ab[q];
    __syncthreads();

    const int cq = tid & 15, rr = tid >> 4;
    float4 acc0 = make_float4(0.f,0.f,0.f,0.f);
    float4 acc1 = make_float4(0.f,0.f,0.f,0.f);
    for (int kq = 0; kq < 32; ++kq){
        float4 w0q = *(float4*)&sW[(kq*4+0)*64 + cq*4];
        float4 w1q = *(float4*)&sW[(kq*4+1)*64 + cq*4];
        float4 w2q = *(float4*)&sW[(kq*4+2)*64 + cq*4];
        float4 w3q = *(float4*)&sW[(kq*4+3)*64 + cq*4];
        float4 a0 = *(float4*)&sA[rr*128 + kq*4];
        float4 a1 = *(float4*)&sA[(rr+16)*128 + kq*4];
        acc0.x = fmaf(a0.x,w0q.x, fmaf(a0.y,w1q.x, fmaf(a0.z,w2q.x, fmaf(a0.w,w3q.x, acc0.x))));
        acc0.y = fmaf(a0.x,w0q.y, fmaf(a0.y,w1q.y, fmaf(a0.z,w2q.y, fmaf(a0.w,w3q.y, acc0.y))));
        acc0.z = fmaf(a0.x,w0q.z, fmaf(a0.y,w1q.z, fmaf(a0.z,w2q.z, fmaf(a0.w,w3q.z, acc0.z))));
        acc0.w = fmaf(a0.x,w0q.w, fmaf(a0.y,w1q.w, fmaf(a0.z,w2q.w, fmaf(a0.w,w3q.w, acc0.w))));
        acc1.x = fmaf(a1.x,w0q.x, fmaf(a1.y,w1q.x, fmaf(a1.z,w2q.x, fmaf(a1.w,w3q.x, acc1.x))));
        acc1.y = fmaf(a1.x,w0q.y, fmaf(a1.y,w1q.y, fmaf(a1.z,w2q.y, fmaf(a1.w,w3q.y, acc1.y))));
        acc1.z = fmaf(a1.x,w0q.z, fmaf(a1.y,w1q.z, fmaf(a1.z,w2q.z, fmaf(a1.w,w3q.z, acc1.z))));
        acc1.w = fmaf(a1.x,w0q.w, fmaf(a1.y,w1q.w, fmaf(a1.z,w2q.w, fmaf(a1.w,w3q.w, acc1.w))));
    }
    const int col0 = cq*4;
    float b0=bias[col0], b1=bias[col0+1], b2=bias[col0+2], b3=bias[col0+3];
    float o0[4] = {acc0.x+b0, acc0.y+b1, acc0.z+b2, acc0.w+b3};
    float o1[4] = {acc1.x+b0, acc1.y+b1, acc1.z+b2, acc1.w+b3};
    int r0 = rt*32 + rr;
    size_t p0 = (size_t)r0*ODIM + col0, p1 = (size_t)(r0+16)*ODIM + col0;
    if (flag[0] != 0.0f){
        bf16* ob = (bf16*)outp;
        #pragma unroll
        for (int i = 0; i < 4; ++i){ ob[p0+i] = __float2bfloat16(o0[i]); ob[p1+i] = __float2bfloat16(o1[i]); }
    } else {
        float* of = (float*)outp;
        *(float4*)&of[p0] = make_float4(o0[0],o0[1],o0[2],o0[3]);
        *(float4*)&of[p1] = make_float4(o1[0],o1[1],o1[2],o1[3]);
    }
}

// ------------- per-batch bitonic sort of e2 (2000 -> pad 2048) --------------------
__global__ void sort_k(const float* __restrict__ e2p, float* __restrict__ e2s, int* __restrict__ sidx,
                       float* __restrict__ wp, float* __restrict__ wn, float* __restrict__ e2m)
{
    __shared__ float v[2048];
    __shared__ int  ix[2048];
    const int b = blockIdx.x, t = threadIdx.x;   // 1024 threads
    for (int i = t; i < 2048; i += 1024){
        v[i]  = (i < NNODE) ? (e2p[b*NNODE + i] + e2p[BN + b*NNODE + i]) : 3.0e38f;
        ix[i] = i;
    }
    __syncthreads();
    for (int size = 2; size <= 2048; size <<= 1){
        for (int stride = size >> 1; stride > 0; stride >>= 1){
            int i = 2*t - (t & (stride-1));
            int j = i + stride;
            bool asc = ((i & size) == 0);
            float vi = v[i], vj = v[j];
            bool sw = asc ? (vi > vj) : (vi < vj);
            if (sw){ v[i]=vj; v[j]=vi; int tm=ix[i]; ix[i]=ix[j]; ix[j]=tm; }
            __syncthreads();
        }
    }
    float mx = v[NNODE-1];
    for (int i = t; i < NNODE; i += 1024){
        float val = v[i];
        e2s [b*NNODE+i] = val;
        sidx[b*NNODE+i] = ix[i];
        wp  [b*NNODE+i] = __expf(val - mx);          // <= 1
        wn  [b*NNODE+i] = __expf(0.2f*(val - mx));   // <= 1
    }
    if (t == 0) e2m[b] = mx;
}

// ------------- pass A: per-chunk partial sums (vector[D] + scalar) ----------------
__global__ void passA_k(const float* __restrict__ Wh, const int* __restrict__ sidx,
    const float* __restrict__ wp, const float* __restrict__ wn,
    float* __restrict__ chunkP, float* __restrict__ chunkN,
    float* __restrict__ schunkP, float* __restrict__ schunkN)
{
    const int b = blockIdx.x / CHK, c = blockIdx.x % CHK, d = threadIdx.x;
    const int base = b*NNODE;
    float sp=0.f, sn=0.f, ssp=0.f, ssn=0.f;
    #pragma unroll 4
    for (int r = c*CKS; r < c*CKS + CKS; ++r){
        int j = sidx[base + r];
        float whv = Wh[((size_t)base + j)*DIM + d];
        float wpv = wp[base + r], wnv = wn[base + r];
        sp = fmaf(wpv, whv, sp);  sn = fmaf(wnv, whv, sn);
        ssp += wpv;  ssn += wnv;
    }
    const int idx = b*CHK + c;
    chunkP[idx*DIM + d] = sp;
    chunkN[idx*DIM + d] = sn;
    if (d == 0){ schunkP[idx] = ssp; schunkN[idx] = ssn; }
}

// ------------- pass C: fixed-trip predicated offset scan + suffix/prefix arrays ----
// The cross-chunk offsets are computed with FIXED trip counts (5 tiles x 25) and
// predicated adds, so the compiler keeps ~25 loads in flight (the passB recipe).
__global__ __launch_bounds__(128) void passC_k(const float* __restrict__ Wh,
    const int* __restrict__ sidx, const float* __restrict__ wp, const float* __restrict__ wn,
    const float* __restrict__ chunkP, const float* __restrict__ chunkN,
    const float* __restrict__ schunkP, const float* __restrict__ schunkN,
    float* __restrict__ Ppos, float* __restrict__ Pneg,
    float* __restrict__ pposs, float* __restrict__ pnegs)
{
    const int b = blockIdx.x / CHK, c = blockIdx.x % CHK, d = threadIdx.x;
    const int base = b*NNODE;
    const size_t pb = (size_t)b*NP1;
    const int r0 = c*CKS, r1 = r0 + CKS;

    // predicated tiled scan over all 125 chunks (uniform trip count -> pipelined)
    float offPd = 0.f, offNd = 0.f;
    const float* cpb = chunkP + (size_t)b*CHK*DIM + d;
    const float* cnb = chunkN + (size_t)b*CHK*DIM + d;
    #pragma unroll
    for (int t = 0; t < 5; ++t){
        float vP[25], vN[25];
        #pragma unroll
        for (int k = 0; k < 25; ++k){
            vP[k] = cpb[(size_t)(t*25 + k)*DIM];
            vN[k] = cnb[(size_t)(t*25 + k)*DIM];
        }
        #pragma unroll
        for (int k = 0; k < 25; ++k){
            int cc = t*25 + k;
            offPd += (cc > c) ? vP[k] : 0.f;
            offNd += (cc < c) ? vN[k] : 0.f;
        }
    }
    // scalar offsets via shared reduction (cheap)
    __shared__ float redP[128], redN[128];
    redP[d] = (d < CHK && d > c) ? schunkP[b*CHK + d] : 0.f;
    redN[d] = (d < c)            ? schunkN[b*CHK + d] : 0.f;
    __syncthreads();
    for (int s = 64; s; s >>= 1){
        if (d < s){ redP[d] += redP[d+s]; redN[d] += redN[d+s]; }
        __syncthreads();
    }
    const float soffPv = redP[0], soffNv = redN[0];

    if (c == CHK-1){
        Ppos[(pb + NNODE)*DIM + d] = 0.f;
        if (d == 0) pposs[pb + NNODE] = 0.f;
    }
    float pr = offPd, spr = soffPv;                      // suffix sums, descending
    for (int r = r1-1; r >= r0; --r){
        int j = sidx[base + r];
        float whv = Wh[((size_t)base + j)*DIM + d];
        float wpv = wp[base + r];
        pr  = fmaf(wpv, whv, pr);
        spr += wpv;
        Ppos[(pb + r)*DIM + d] = pr;
        if (d == 0) pposs[pb + r] = spr;
    }
    float nr = offNd, snr = soffNv;                      // prefix sums (exclusive)
    for (int r = r0; r < r1; ++r){
        int j = sidx[base + r];
        float whv = Wh[((size_t)base + j)*DIM + d];
        float wnv = wn[base + r];
        Pneg[(pb + r)*DIM + d] = nr;
        if (d == 0) pnegs[pb + r] = snr;
        nr  = fmaf(wnv, whv, nr);
        snr += wnv;
    }
    if (c == CHK-1){
        Pneg[(pb + NNODE)*DIM + d] = nr;
        if (d == 0) pnegs[pb + NNODE] = snr;
    }
}

// ------------- output, 16 rows per block: parallel binsearch then stream -----------
__global__ __launch_bounds__(128) void out16_k(const float* __restrict__ e1p,
    const float* __restrict__ e2s, const float* __restrict__ e2m,
    const float* __restrict__ Ppos, const float* __restrict__ Pneg,
    const float* __restrict__ pposs, const float* __restrict__ pnegs, float* __restrict__ h)
{
    __shared__ int   slo[CKS];
    __shared__ float sps[CKS], sns[CKS];
    const int b = blockIdx.x / CHK, c = blockIdx.x % CHK, d = threadIdx.x;
    const int base = b*NNODE, r0 = c*CKS;
    const size_t pb = (size_t)b*NP1;

    if (d < CKS){
        int row = base + r0 + d;
        float e1v = e1p[row] + e1p[BN + row];
        float s = e1v + e2m[b];
        float m = (s >= 0.f) ? s : 0.2f*s;
        sps[d] = __expf(s - m);
        sns[d] = __expf(0.2f*s - m);
        const float* es = e2s + base;
        float t = -e1v;
        int lo = 0, hi = NNODE;
        while (lo < hi){ int mid = (lo+hi) >> 1; if (es[mid] < t) lo = mid+1; else hi = mid; }
        slo[d] = lo;
    }
    __syncthreads();
    #pragma unroll 4
    for (int k = 0; k < CKS; ++k){
        int row = base + r0 + k;
        size_t kb = pb + slo[k];
        float numer = sps[k]*Ppos[kb*DIM + d] + sns[k]*Pneg[kb*DIM + d];
        float Z     = sps[k]*pposs[kb]        + sns[k]*pnegs[kb];
        float q = numer / Z;
        h[(size_t)row*DIM + d] = (q > 0.f) ? q : ((q == q) ? 0.f : q);
    }
}

extern "C" void kernel_launch(void* const* d_in, const int* in_sizes, int n_in,
                              void* d_out, int out_size, void* d_ws, size_t ws_size,
                              hipStream_t stream)
{
    (void)in_sizes; (void)n_in; (void)out_size; (void)ws_size;

    float* f = (float*)d_ws;
    float* flag    = f;  f += 4;
    float* cvt     = f;  f += CVT_TOT;                 // 0.56 MB
    float* h       = f;  f += (size_t)BN*DIM;          // 16.4 MB
    float* Wh      = f;  f += (size_t)BN*DIM;          // 16.4 MB
    float* Ppos    = f;  f += (size_t)BATCH*NP1*DIM;   // 16.4 MB
    float* Pneg    = f;  f += (size_t)BATCH*NP1*DIM;   // 16.4 MB
    float* chunkP  = f;  f += BATCH*CHK*DIM;           // 1 MB
    float* chunkN  = f;  f += BATCH*CHK*DIM;           // 1 MB
    float* schunkP = f;  f += BATCH*CHK;
    float* schunkN = f;  f += BATCH*CHK;
    float* e1p     = f;  f += 2*BN;                    // two 64-col partials
    float* e2p     = f;  f += 2*BN;
    float* e2s     = f;  f += BN;
    float* wp      = f;  f += BN;
    float* wn      = f;  f += BN;
    float* pposs   = f;  f += BATCH*NP1;
    float* pnegs   = f;  f += BATCH*NP1;
    float* e2m     = f;  f += 16;
    int*   sidx    = (int*)f;

    // 1. convert all inputs to fp32 (sniff embedded)
    InPtrs ip;
    for (int i = 0; i < 10; ++i) ip.p[i] = d_in[i];
    convert_all_k<<<(CVT_TOT+255)/256, 256, 0, stream>>>(ip, cvt, flag);

    // 2. fused encoder (enc0 + gemm)
    encgemm_k<<<dim3(BN/32, 2), 256, 0, stream>>>(cvt, h);

    // 3. GAT layers (exact separable-softmax factorization)
    for (int l = 0; l < NLAYER; ++l){
        gatgemm_k<<<dim3(BN/32, 2), 256, 0, stream>>>(h, cvt + OFF_GW + l*DIM*DIM,
                                                      cvt + OFF_GA1 + l*DIM, cvt + OFF_GA2 + l*DIM,
                                                      Wh, e1p, e2p);
        sort_k<<<BATCH, 1024, 0, stream>>>(e2p, e2s, sidx, wp, wn, e2m);
        passA_k<<<BATCH*CHK, DIM, 0, stream>>>(Wh, sidx, wp, wn, chunkP, chunkN, schunkP, schunkN);
        passC_k<<<BATCH*CHK, DIM, 0, stream>>>(Wh, sidx, wp, wn, chunkP, chunkN,
                                               schunkP, schunkN, Ppos, Pneg, pposs, pnegs);
        out16_k<<<BATCH*CHK, DIM, 0, stream>>>(e1p, e2s, e2m, Ppos, Pneg, pposs, pnegs, h);
    }

    // 4. projection, output dtype per flag
    gemmout_k<<<BN/32, 256, 0, stream>>>(h, cvt + OFF_PW, cvt + OFF_PB, d_out, flag);
}

// Round 13
// 365.295 us; speedup vs baseline: 1.2670x; 1.2670x over previous
//
#include <hip/hip_runtime.h>
#include <hip/hip_bf16.h>

using bf16 = __hip_bfloat16;

#define BATCH 16
#define NNODE 2000
#define DIM   128
#define ODIM  64
#define NLAYER 3
#define BN    (BATCH*NNODE)   // 32000
#define NP1   (NNODE+1)       // 2001
#define CHK   125             // chunks per batch
#define CKS   16              // chunk size (125*16 = 2000)

// converted-input element offsets inside cvt buffer
#define OFF_COORDS 0
#define OFF_EW0    64000
#define OFF_EB0    64256
#define OFF_EW1    64384
#define OFF_EB1    80768
#define OFF_GW     80896
#define OFF_GA1    130048
#define OFF_GA2    130432
#define OFF_PW     130816
#define OFF_PB     139008
#define CVT_TOT    139072

struct InPtrs { const void* p[10]; };

// ------------- convert ALL inputs to fp32 (sniff embedded per block) ---------------
__global__ void convert_all_k(InPtrs in, float* __restrict__ dst, float* __restrict__ flag)
{
    __shared__ int scnt[256];
    const unsigned short* raw = (const unsigned short*)in.p[0];
    int t = threadIdx.x, c = 0;
    for (int k = t; k < 2048; k += 256){
        unsigned short u = raw[2*k];                 // first 8 KB, safe either dtype
        int e = (u >> 7) & 0xFF;
        if (e >= 100 && e <= 140) ++c;
    }
    scnt[t] = c;
    __syncthreads();
    for (int s = 128; s; s >>= 1){ if (t < s) scnt[t] += scnt[t+s]; __syncthreads(); }
    const bool isbf16 = (scnt[0] >= 1800);
    if (blockIdx.x == 0 && t == 0) flag[0] = isbf16 ? 1.0f : 0.0f;

    const int off[11] = {OFF_COORDS,OFF_EW0,OFF_EB0,OFF_EW1,OFF_EB1,
                         OFF_GW,OFF_GA1,OFF_GA2,OFF_PW,OFF_PB,CVT_TOT};
    int i = blockIdx.x*256 + t;
    if (i >= CVT_TOT) return;
    int seg = 0;
    #pragma unroll
    for (int s = 1; s < 10; ++s) if (i >= off[s]) seg = s;
    int li = i - off[seg];
    if (isbf16) dst[i] = __bfloat162float(((const bf16*)in.p[seg])[li]);
    else        dst[i] = ((const float*)in.p[seg])[li];
}

// ------------- fused encoder: h = relu(coords@w0+b0) @ w1 + b1 ---------------------
__global__ __launch_bounds__(256) void encgemm_k(const float* __restrict__ cvt,
                                                 float* __restrict__ out)
{
    __shared__ __align__(16) float sW[128*64];   // [k][cc] 32 KB
    __shared__ __align__(16) float sA[32*128];   // [r][k]  16 KB
    const int rt = blockIdx.x, cb = blockIdx.y, tid = threadIdx.x;
    const float* W      = cvt + OFF_EW1;
    const float* bias   = cvt + OFF_EB1;
    const float* coords = cvt + OFF_COORDS;
    const float* w0     = cvt + OFF_EW0;
    const float* b0v    = cvt + OFF_EB0;

    for (int e = tid; e < 128*64; e += 256){
        int k = e >> 6, cc = e & 63;
        sW[e] = W[k*DIM + cb*64 + cc];
    }
    for (int e = tid; e < 32*128; e += 256){
        int r = e >> 7, k = e & 127;
        int node = rt*32 + r;
        float c0 = coords[node*2+0], c1 = coords[node*2+1];
        float v = fmaf(c0, w0[k], fmaf(c1, w0[DIM+k], b0v[k]));
        sA[e] = v > 0.f ? v : 0.f;
    }
    __syncthreads();

    const int cq = tid & 15, rr = tid >> 4;
    float4 acc0 = make_float4(0.f,0.f,0.f,0.f);
    float4 acc1 = make_float4(0.f,0.f,0.f,0.f);
    for (int kq = 0; kq < 32; ++kq){
        float4 w0q = *(float4*)&sW[(kq*4+0)*64 + cq*4];
        float4 w1q = *(float4*)&sW[(kq*4+1)*64 + cq*4];
        float4 w2q = *(float4*)&sW[(kq*4+2)*64 + cq*4];
        float4 w3q = *(float4*)&sW[(kq*4+3)*64 + cq*4];
        float4 a0 = *(float4*)&sA[rr*128 + kq*4];
        float4 a1 = *(float4*)&sA[(rr+16)*128 + kq*4];
        acc0.x = fmaf(a0.x,w0q.x, fmaf(a0.y,w1q.x, fmaf(a0.z,w2q.x, fmaf(a0.w,w3q.x, acc0.x))));
        acc0.y = fmaf(a0.x,w0q.y, fmaf(a0.y,w1q.y, fmaf(a0.z,w2q.y, fmaf(a0.w,w3q.y, acc0.y))));
        acc0.z = fmaf(a0.x,w0q.z, fmaf(a0.y,w1q.z, fmaf(a0.z,w2q.z, fmaf(a0.w,w3q.z, acc0.z))));
        acc0.w = fmaf(a0.x,w0q.w, fmaf(a0.y,w1q.w, fmaf(a0.z,w2q.w, fmaf(a0.w,w3q.w, acc0.w))));
        acc1.x = fmaf(a1.x,w0q.x, fmaf(a1.y,w1q.x, fmaf(a1.z,w2q.x, fmaf(a1.w,w3q.x, acc1.x))));
        acc1.y = fmaf(a1.x,w0q.y, fmaf(a1.y,w1q.y, fmaf(a1.z,w2q.y, fmaf(a1.w,w3q.y, acc1.y))));
        acc1.z = fmaf(a1.x,w0q.z, fmaf(a1.y,w1q.z, fmaf(a1.z,w2q.z, fmaf(a1.w,w3q.z, acc1.z))));
        acc1.w = fmaf(a1.x,w0q.w, fmaf(a1.y,w1q.w, fmaf(a1.z,w2q.w, fmaf(a1.w,w3q.w, acc1.w))));
    }
    const int col0 = cb*64 + cq*4;
    float b0=bias[col0], b1=bias[col0+1], b2=bias[col0+2], b3=bias[col0+3];
    int r0 = rt*32 + rr;
    *(float4*)&out[(size_t)r0*DIM + col0]      = make_float4(acc0.x+b0, acc0.y+b1, acc0.z+b2, acc0.w+b3);
    *(float4*)&out[(size_t)(r0+16)*DIM + col0] = make_float4(acc1.x+b0, acc1.y+b1, acc1.z+b2, acc1.w+b3);
}

// ------------- GAT GEMM: Wh = h @ W, fused e1/e2 64-col partial dots ---------------
__global__ __launch_bounds__(256) void gatgemm_k(const float* __restrict__ A,
    const float* __restrict__ W, const float* __restrict__ a1, const float* __restrict__ a2,
    float* __restrict__ out, float* __restrict__ e1p, float* __restrict__ e2p)
{
    __shared__ __align__(16) float sW[128*64];
    __shared__ __align__(16) float sA[32*128];
    const int rt = blockIdx.x, cb = blockIdx.y, tid = threadIdx.x;

    for (int e = tid; e < 128*64; e += 256){
        int k = e >> 6, cc = e & 63;
        sW[e] = W[k*DIM + cb*64 + cc];
    }
    const float4* Ab = (const float4*)(A + (size_t)rt*32*128);
    float4* sA4 = (float4*)sA;
    for (int q = tid; q < 32*32; q += 256) sA4[q] = Ab[q];
    __syncthreads();

    const int cq = tid & 15, rr = tid >> 4;
    float4 acc0 = make_float4(0.f,0.f,0.f,0.f);
    float4 acc1 = make_float4(0.f,0.f,0.f,0.f);
    for (int kq = 0; kq < 32; ++kq){
        float4 w0q = *(float4*)&sW[(kq*4+0)*64 + cq*4];
        float4 w1q = *(float4*)&sW[(kq*4+1)*64 + cq*4];
        float4 w2q = *(float4*)&sW[(kq*4+2)*64 + cq*4];
        float4 w3q = *(float4*)&sW[(kq*4+3)*64 + cq*4];
        float4 a0 = *(float4*)&sA[rr*128 + kq*4];
        float4 a1q = *(float4*)&sA[(rr+16)*128 + kq*4];
        acc0.x = fmaf(a0.x,w0q.x, fmaf(a0.y,w1q.x, fmaf(a0.z,w2q.x, fmaf(a0.w,w3q.x, acc0.x))));
        acc0.y = fmaf(a0.x,w0q.y, fmaf(a0.y,w1q.y, fmaf(a0.z,w2q.y, fmaf(a0.w,w3q.y, acc0.y))));
        acc0.z = fmaf(a0.x,w0q.z, fmaf(a0.y,w1q.z, fmaf(a0.z,w2q.z, fmaf(a0.w,w3q.z, acc0.z))));
        acc0.w = fmaf(a0.x,w0q.w, fmaf(a0.y,w1q.w, fmaf(a0.z,w2q.w, fmaf(a0.w,w3q.w, acc0.w))));
        acc1.x = fmaf(a1q.x,w0q.x, fmaf(a1q.y,w1q.x, fmaf(a1q.z,w2q.x, fmaf(a1q.w,w3q.x, acc1.x))));
        acc1.y = fmaf(a1q.x,w0q.y, fmaf(a1q.y,w1q.y, fmaf(a1q.z,w2q.y, fmaf(a1q.w,w3q.y, acc1.y))));
        acc1.z = fmaf(a1q.x,w0q.z, fmaf(a1q.y,w1q.z, fmaf(a1q.z,w2q.z, fmaf(a1q.w,w3q.z, acc1.z))));
        acc1.w = fmaf(a1q.x,w0q.w, fmaf(a1q.y,w1q.w, fmaf(a1q.z,w2q.w, fmaf(a1q.w,w3q.w, acc1.w))));
    }
    const int col0 = cb*64 + cq*4;
    int r0 = rt*32 + rr;
    *(float4*)&out[(size_t)r0*DIM + col0]      = acc0;
    *(float4*)&out[(size_t)(r0+16)*DIM + col0] = acc1;

    float a1v0=a1[col0], a1v1=a1[col0+1], a1v2=a1[col0+2], a1v3=a1[col0+3];
    float a2v0=a2[col0], a2v1=a2[col0+1], a2v2=a2[col0+2], a2v3=a2[col0+3];
    float p1r0 = acc0.x*a1v0 + acc0.y*a1v1 + acc0.z*a1v2 + acc0.w*a1v3;
    float p2r0 = acc0.x*a2v0 + acc0.y*a2v1 + acc0.z*a2v2 + acc0.w*a2v3;
    float p1r1 = acc1.x*a1v0 + acc1.y*a1v1 + acc1.z*a1v2 + acc1.w*a1v3;
    float p2r1 = acc1.x*a2v0 + acc1.y*a2v1 + acc1.z*a2v2 + acc1.w*a2v3;
    #pragma unroll
    for (int msk = 1; msk < 16; msk <<= 1){
        p1r0 += __shfl_xor(p1r0, msk); p2r0 += __shfl_xor(p2r0, msk);
        p1r1 += __shfl_xor(p1r1, msk); p2r1 += __shfl_xor(p2r1, msk);
    }
    if (cq == 0){
        e1p[cb*BN + r0]    = p1r0;  e2p[cb*BN + r0]    = p2r0;
        e1p[cb*BN + r0+16] = p1r1;  e2p[cb*BN + r0+16] = p2r1;
    }
}

// ------------- final projection GEMM, output dtype per flag ------------------------
__global__ __launch_bounds__(256) void gemmout_k(const float* __restrict__ A,
    const float* __restrict__ W, const float* __restrict__ bias,
    void* __restrict__ outp, const float* __restrict__ flag)
{
    __shared__ __align__(16) float sW[128*64];
    __shared__ __align__(16) float sA[32*128];
    const int rt = blockIdx.x, tid = threadIdx.x;
    for (int e = tid; e < 128*64; e += 256){
        int k = e >> 6, cc = e & 63;
        sW[e] = W[k*ODIM + cc];
    }
    const float4* Ab = (const float4*)(A + (size_t)rt*32*128);
    float4* sA4 = (float4*)sA;
    for (int q = tid; q < 32*32; q += 256) sA4[q] = Ab[q];
    __syncthreads();

    const int cq = tid & 15, rr = tid >> 4;
    float4 acc0 = make_float4(0.f,0.f,0.f,0.f);
    float4 acc1 = make_float4(0.f,0.f,0.f,0.f);
    for (int kq = 0; kq < 32; ++kq){
        float4 w0q = *(float4*)&sW[(kq*4+0)*64 + cq*4];
        float4 w1q = *(float4*)&sW[(kq*4+1)*64 + cq*4];
        float4 w2q = *(float4*)&sW[(kq*4+2)*64 + cq*4];
        float4 w3q = *(float4*)&sW[(kq*4+3)*64 + cq*4];
        float4 a0 = *(float4*)&sA[rr*128 + kq*4];
        float4 a1 = *(float4*)&sA[(rr+16)*128 + kq*4];
        acc0.x = fmaf(a0.x,w0q.x, fmaf(a0.y,w1q.x, fmaf(a0.z,w2q.x, fmaf(a0.w,w3q.x, acc0.x))));
        acc0.y = fmaf(a0.x,w0q.y, fmaf(a0.y,w1q.y, fmaf(a0.z,w2q.y, fmaf(a0.w,w3q.y, acc0.y))));
        acc0.z = fmaf(a0.x,w0q.z, fmaf(a0.y,w1q.z, fmaf(a0.z,w2q.z, fmaf(a0.w,w3q.z, acc0.z))));
        acc0.w = fmaf(a0.x,w0q.w, fmaf(a0.y,w1q.w, fmaf(a0.z,w2q.w, fmaf(a0.w,w3q.w, acc0.w))));
        acc1.x = fmaf(a1.x,w0q.x, fmaf(a1.y,w1q.x, fmaf(a1.z,w2q.x, fmaf(a1.w,w3q.x, acc1.x))));
        acc1.y = fmaf(a1.x,w0q.y, fmaf(a1.y,w1q.y, fmaf(a1.z,w2q.y, fmaf(a1.w,w3q.y, acc1.y))));
        acc1.z = fmaf(a1.x,w0q.z, fmaf(a1.y,w1q.z, fmaf(a1.z,w2q.z, fmaf(a1.w,w3q.z, acc1.z))));
        acc1.w = fmaf(a1.x,w0q.w, fmaf(a1.y,w1q.w, fmaf(a1.z,w2q.w, fmaf(a1.w,w3q.w, acc1.w))));
    }
    const int col0 = cq*4;
    float b0=bias[col0], b1=bias[col0+1], b2=bias[col0+2], b3=bias[col0+3];
    float o0[4] = {acc0.x+b0, acc0.y+b1, acc0.z+b2, acc0.w+b3};
    float o1[4] = {acc1.x+b0, acc1.y+b1, acc1.z+b2, acc1.w+b3};
    int r0 = rt*32 + rr;
    size_t p0 = (size_t)r0*ODIM + col0, p1 = (size_t)(r0+16)*ODIM + col0;
    if (flag[0] != 0.0f){
        bf16* ob = (bf16*)outp;
        #pragma unroll
        for (int i = 0; i < 4; ++i){ ob[p0+i] = __float2bfloat16(o0[i]); ob[p1+i] = __float2bfloat16(o1[i]); }
    } else {
        float* of = (float*)outp;
        *(float4*)&of[p0] = make_float4(o0[0],o0[1],o0[2],o0[3]);
        *(float4*)&of[p1] = make_float4(o1[0],o1[1],o1[2],o1[3]);
    }
}

// ------------- per-batch bitonic sort of e2 (2000 -> pad 2048) --------------------
__global__ void sort_k(const float* __restrict__ e2p, float* __restrict__ e2s, int* __restrict__ sidx,
                       float* __restrict__ wp, float* __restrict__ wn, float* __restrict__ e2m)
{
    __shared__ float v[2048];
    __shared__ int  ix[2048];
    const int b = blockIdx.x, t = threadIdx.x;   // 1024 threads
    for (int i = t; i < 2048; i += 1024){
        v[i]  = (i < NNODE) ? (e2p[b*NNODE + i] + e2p[BN + b*NNODE + i]) : 3.0e38f;
        ix[i] = i;
    }
    __syncthreads();
    for (int size = 2; size <= 2048; size <<= 1){
        for (int stride = size >> 1; stride > 0; stride >>= 1){
            int i = 2*t - (t & (stride-1));
            int j = i + stride;
            bool asc = ((i & size) == 0);
            float vi = v[i], vj = v[j];
            bool sw = asc ? (vi > vj) : (vi < vj);
            if (sw){ v[i]=vj; v[j]=vi; int tm=ix[i]; ix[i]=ix[j]; ix[j]=tm; }
            __syncthreads();
        }
    }
    float mx = v[NNODE-1];
    for (int i = t; i < NNODE; i += 1024){
        float val = v[i];
        e2s [b*NNODE+i] = val;
        sidx[b*NNODE+i] = ix[i];
        wp  [b*NNODE+i] = __expf(val - mx);          // <= 1
        wn  [b*NNODE+i] = __expf(0.2f*(val - mx));   // <= 1
    }
    if (t == 0) e2m[b] = mx;
}

// ------------- pass A: per-chunk partial sums (vector[D] + scalar) ----------------
__global__ void passA_k(const float* __restrict__ Wh, const int* __restrict__ sidx,
    const float* __restrict__ wp, const float* __restrict__ wn,
    float* __restrict__ chunkP, float* __restrict__ chunkN,
    float* __restrict__ schunkP, float* __restrict__ schunkN)
{
    const int b = blockIdx.x / CHK, c = blockIdx.x % CHK, d = threadIdx.x;
    const int base = b*NNODE;
    float sp=0.f, sn=0.f, ssp=0.f, ssn=0.f;
    #pragma unroll 4
    for (int r = c*CKS; r < c*CKS + CKS; ++r){
        int j = sidx[base + r];
        float whv = Wh[((size_t)base + j)*DIM + d];
        float wpv = wp[base + r], wnv = wn[base + r];
        sp = fmaf(wpv, whv, sp);  sn = fmaf(wnv, whv, sn);
        ssp += wpv;  ssn += wnv;
    }
    const int idx = b*CHK + c;
    chunkP[idx*DIM + d] = sp;
    chunkN[idx*DIM + d] = sn;
    if (d == 0){ schunkP[idx] = ssp; schunkN[idx] = ssn; }
}

// ------------- pass B: cross-chunk suffix (P) / prefix (N) offsets (exclusive) -----
__global__ __launch_bounds__(256) void passB_k(
    const float* __restrict__ chunkP, const float* __restrict__ chunkN,
    const float* __restrict__ schunkP, const float* __restrict__ schunkN,
    float* __restrict__ offP, float* __restrict__ offN,
    float* __restrict__ soffP, float* __restrict__ soffN)
{
    const int b = blockIdx.x, tid = threadIdx.x;
    const bool doP = (blockIdx.y == 0);
    const float* chunk  = doP ? chunkP  : chunkN;
    const float* schunk = doP ? schunkP : schunkN;
    float* off  = doP ? offP  : offN;
    float* soff = doP ? soffP : soffN;

    if (tid < 128){
        const int d = tid;
        float acc = 0.f, v[25];
        #pragma unroll
        for (int t = 0; t < 5; ++t){
            const int c0 = doP ? (4-t)*25 : t*25;
            #pragma unroll
            for (int k = 0; k < 25; ++k) v[k] = chunk[(b*CHK + c0 + k)*DIM + d];
            if (doP){
                #pragma unroll
                for (int k = 24; k >= 0; --k){ off[(b*CHK + c0 + k)*DIM + d] = acc; acc += v[k]; }
            } else {
                #pragma unroll
                for (int k = 0; k < 25; ++k){ off[(b*CHK + c0 + k)*DIM + d] = acc; acc += v[k]; }
            }
        }
    } else if (tid == 128){
        float sacc = 0.f, sv[25];
        #pragma unroll
        for (int t = 0; t < 5; ++t){
            const int c0 = doP ? (4-t)*25 : t*25;
            #pragma unroll
            for (int k = 0; k < 25; ++k) sv[k] = schunk[b*CHK + c0 + k];
            if (doP){
                #pragma unroll
                for (int k = 24; k >= 0; --k){ soff[b*CHK + c0 + k] = sacc; sacc += sv[k]; }
            } else {
                #pragma unroll
                for (int k = 0; k < 25; ++k){ soff[b*CHK + c0 + k] = sacc; sacc += sv[k]; }
            }
        }
    }
}

// ------------- pass C: full suffix (pos) / prefix (neg) arrays over sorted order ---
__global__ void passC_k(const float* __restrict__ Wh, const int* __restrict__ sidx,
    const float* __restrict__ wp, const float* __restrict__ wn,
    const float* __restrict__ offP, const float* __restrict__ offN,
    const float* __restrict__ soffP, const float* __restrict__ soffN,
    float* __restrict__ Ppos, float* __restrict__ Pneg,
    float* __restrict__ pposs, float* __restrict__ pnegs)
{
    const int b = blockIdx.x / CHK, c = blockIdx.x % CHK, d = threadIdx.x;
    const int base = b*NNODE;
    const size_t pb = (size_t)b*NP1;
    const int idx = b*CHK + c;
    const int r0 = c*CKS, r1 = r0 + CKS;

    if (c == CHK-1){
        Ppos[(pb + NNODE)*DIM + d] = 0.f;
        if (d == 0) pposs[pb + NNODE] = 0.f;
    }
    float pr = offP[idx*DIM + d], spr = soffP[idx];     // suffix sums, descending
    for (int r = r1-1; r >= r0; --r){
        int j = sidx[base + r];
        float whv = Wh[((size_t)base + j)*DIM + d];
        float wpv = wp[base + r];
        pr  = fmaf(wpv, whv, pr);
        spr += wpv;
        Ppos[(pb + r)*DIM + d] = pr;
        if (d == 0) pposs[pb + r] = spr;
    }
    float nr = offN[idx*DIM + d], snr = soffN[idx];     // prefix sums (exclusive)
    for (int r = r0; r < r1; ++r){
        int j = sidx[base + r];
        float whv = Wh[((size_t)base + j)*DIM + d];
        float wnv = wn[base + r];
        Pneg[(pb + r)*DIM + d] = nr;
        if (d == 0) pnegs[pb + r] = snr;
        nr  = fmaf(wnv, whv, nr);
        snr += wnv;
    }
    if (c == CHK-1){
        Pneg[(pb + NNODE)*DIM + d] = nr;
        if (d == 0) pnegs[pb + NNODE] = snr;
    }
}

// ------------- output, 16 rows per block: parallel binsearch then stream -----------
__global__ __launch_bounds__(128) void out16_k(const float* __restrict__ e1p,
    const float* __restrict__ e2s, const float* __restrict__ e2m,
    const float* __restrict__ Ppos, const float* __restrict__ Pneg,
    const float* __restrict__ pposs, const float* __restrict__ pnegs, float* __restrict__ h)
{
    __shared__ int   slo[CKS];
    __shared__ float sps[CKS], sns[CKS];
    const int b = blockIdx.x / CHK, c = blockIdx.x % CHK, d = threadIdx.x;
    const int base = b*NNODE, r0 = c*CKS;
    const size_t pb = (size_t)b*NP1;

    if (d < CKS){
        int row = base + r0 + d;
        float e1v = e1p[row] + e1p[BN + row];
        float s = e1v + e2m[b];
        float m = (s >= 0.f) ? s : 0.2f*s;
        sps[d] = __expf(s - m);
        sns[d] = __expf(0.2f*s - m);
        const float* es = e2s + base;
        float t = -e1v;
        int lo = 0, hi = NNODE;
        while (lo < hi){ int mid = (lo+hi) >> 1; if (es[mid] < t) lo = mid+1; else hi = mid; }
        slo[d] = lo;
    }
    __syncthreads();
    #pragma unroll 4
    for (int k = 0; k < CKS; ++k){
        int row = base + r0 + k;
        size_t kb = pb + slo[k];
        float numer = sps[k]*Ppos[kb*DIM + d] + sns[k]*Pneg[kb*DIM + d];
        float Z     = sps[k]*pposs[kb]        + sns[k]*pnegs[kb];
        float q = numer / Z;
        h[(size_t)row*DIM + d] = (q > 0.f) ? q : ((q == q) ? 0.f : q);
    }
}

extern "C" void kernel_launch(void* const* d_in, const int* in_sizes, int n_in,
                              void* d_out, int out_size, void* d_ws, size_t ws_size,
                              hipStream_t stream)
{
    (void)in_sizes; (void)n_in; (void)out_size; (void)ws_size;

    float* f = (float*)d_ws;
    float* flag    = f;  f += 4;
    float* cvt     = f;  f += CVT_TOT;                 // 0.56 MB
    float* h       = f;  f += (size_t)BN*DIM;          // 16.4 MB
    float* Wh      = f;  f += (size_t)BN*DIM;          // 16.4 MB
    float* Ppos    = f;  f += (size_t)BATCH*NP1*DIM;   // 16.4 MB
    float* Pneg    = f;  f += (size_t)BATCH*NP1*DIM;   // 16.4 MB
    float* chunkP  = f;  f += BATCH*CHK*DIM;           // 1 MB
    float* chunkN  = f;  f += BATCH*CHK*DIM;           // 1 MB
    float* offP    = f;  f += BATCH*CHK*DIM;           // 1 MB
    float* offN    = f;  f += BATCH*CHK*DIM;           // 1 MB
    float* schunkP = f;  f += BATCH*CHK;
    float* schunkN = f;  f += BATCH*CHK;
    float* soffP   = f;  f += BATCH*CHK;
    float* soffN   = f;  f += BATCH*CHK;
    float* e1p     = f;  f += 2*BN;                    // two 64-col partials
    float* e2p     = f;  f += 2*BN;
    float* e2s     = f;  f += BN;
    float* wp      = f;  f += BN;
    float* wn      = f;  f += BN;
    float* pposs   = f;  f += BATCH*NP1;
    float* pnegs   = f;  f += BATCH*NP1;
    float* e2m     = f;  f += 16;
    int*   sidx    = (int*)f;

    // 1. convert all inputs to fp32 (sniff embedded)
    InPtrs ip;
    for (int i = 0; i < 10; ++i) ip.p[i] = d_in[i];
    convert_all_k<<<(CVT_TOT+255)/256, 256, 0, stream>>>(ip, cvt, flag);

    // 2. fused encoder (enc0 + gemm)
    encgemm_k<<<dim3(BN/32, 2), 256, 0, stream>>>(cvt, h);

    // 3. GAT layers (exact separable-softmax factorization)
    for (int l = 0; l < NLAYER; ++l){
        gatgemm_k<<<dim3(BN/32, 2), 256, 0, stream>>>(h, cvt + OFF_GW + l*DIM*DIM,
                                                      cvt + OFF_GA1 + l*DIM, cvt + OFF_GA2 + l*DIM,
                                                      Wh, e1p, e2p);
        sort_k<<<BATCH, 1024, 0, stream>>>(e2p, e2s, sidx, wp, wn, e2m);
        passA_k<<<BATCH*CHK, DIM, 0, stream>>>(Wh, sidx, wp, wn, chunkP, chunkN, schunkP, schunkN);
        passB_k<<<dim3(BATCH, 2), 256, 0, stream>>>(chunkP, chunkN, schunkP, schunkN,
                                                    offP, offN, soffP, soffN);
        passC_k<<<BATCH*CHK, DIM, 0, stream>>>(Wh, sidx, wp, wn, offP, offN, soffP, soffN,
                                               Ppos, Pneg, pposs, pnegs);
        out16_k<<<BATCH*CHK, DIM, 0, stream>>>(e1p, e2s, e2m, Ppos, Pneg, pposs, pnegs, h);
    }

    // 4. projection, output dtype per flag
    gemmout_k<<<BN/32, 256, 0, stream>>>(h, cvt + OFF_PW, cvt + OFF_PB, d_out, flag);
}

// Round 14
// 357.541 us; speedup vs baseline: 1.2944x; 1.0217x over previous
//
#include <hip/hip_runtime.h>
#include <hip/hip_bf16.h>

using bf16 = __hip_bfloat16;

#define BATCH 16
#define NNODE 2000
#define DIM   128
#define ODIM  64
#define NLAYER 3
#define BN    (BATCH*NNODE)   // 32000
#define NP1   (NNODE+1)       // 2001
#define CHK   125             // chunks per batch
#define CKS   16              // chunk size (125*16 = 2000)

// converted-input element offsets inside cvt buffer
#define OFF_COORDS 0
#define OFF_EW0    64000
#define OFF_EB0    64256
#define OFF_EW1    64384
#define OFF_EB1    80768
#define OFF_GW     80896
#define OFF_GA1    130048
#define OFF_GA2    130432
#define OFF_PW     130816
#define OFF_PB     139008
#define CVT_TOT    139072

struct InPtrs { const void* p[10]; };

// ------------- convert ALL inputs to fp32 (sniff embedded per block) ---------------
__global__ void convert_all_k(InPtrs in, float* __restrict__ dst, float* __restrict__ flag)
{
    __shared__ int scnt[256];
    const unsigned short* raw = (const unsigned short*)in.p[0];
    int t = threadIdx.x, c = 0;
    for (int k = t; k < 2048; k += 256){
        unsigned short u = raw[2*k];                 // first 8 KB, safe either dtype
        int e = (u >> 7) & 0xFF;
        if (e >= 100 && e <= 140) ++c;
    }
    scnt[t] = c;
    __syncthreads();
    for (int s = 128; s; s >>= 1){ if (t < s) scnt[t] += scnt[t+s]; __syncthreads(); }
    const bool isbf16 = (scnt[0] >= 1800);
    if (blockIdx.x == 0 && t == 0) flag[0] = isbf16 ? 1.0f : 0.0f;

    const int off[11] = {OFF_COORDS,OFF_EW0,OFF_EB0,OFF_EW1,OFF_EB1,
                         OFF_GW,OFF_GA1,OFF_GA2,OFF_PW,OFF_PB,CVT_TOT};
    int i = blockIdx.x*256 + t;
    if (i >= CVT_TOT) return;
    int seg = 0;
    #pragma unroll
    for (int s = 1; s < 10; ++s) if (i >= off[s]) seg = s;
    int li = i - off[seg];
    if (isbf16) dst[i] = __bfloat162float(((const bf16*)in.p[seg])[li]);
    else        dst[i] = ((const float*)in.p[seg])[li];
}

// ------------- fused encoder: h = relu(coords@w0+b0) @ w1 + b1 ---------------------
__global__ __launch_bounds__(256) void encgemm_k(const float* __restrict__ cvt,
                                                 float* __restrict__ out)
{
    __shared__ __align__(16) float sW[128*64];   // [k][cc] 32 KB
    __shared__ __align__(16) float sA[32*128];   // [r][k]  16 KB
    const int rt = blockIdx.x, cb = blockIdx.y, tid = threadIdx.x;
    const float* W      = cvt + OFF_EW1;
    const float* bias   = cvt + OFF_EB1;
    const float* coords = cvt + OFF_COORDS;
    const float* w0     = cvt + OFF_EW0;
    const float* b0v    = cvt + OFF_EB0;

    for (int e = tid; e < 128*64; e += 256){
        int k = e >> 6, cc = e & 63;
        sW[e] = W[k*DIM + cb*64 + cc];
    }
    for (int e = tid; e < 32*128; e += 256){
        int r = e >> 7, k = e & 127;
        int node = rt*32 + r;
        float c0 = coords[node*2+0], c1 = coords[node*2+1];
        float v = fmaf(c0, w0[k], fmaf(c1, w0[DIM+k], b0v[k]));
        sA[e] = v > 0.f ? v : 0.f;
    }
    __syncthreads();

    const int cq = tid & 15, rr = tid >> 4;
    float4 acc0 = make_float4(0.f,0.f,0.f,0.f);
    float4 acc1 = make_float4(0.f,0.f,0.f,0.f);
    for (int kq = 0; kq < 32; ++kq){
        float4 w0q = *(float4*)&sW[(kq*4+0)*64 + cq*4];
        float4 w1q = *(float4*)&sW[(kq*4+1)*64 + cq*4];
        float4 w2q = *(float4*)&sW[(kq*4+2)*64 + cq*4];
        float4 w3q = *(float4*)&sW[(kq*4+3)*64 + cq*4];
        float4 a0 = *(float4*)&sA[rr*128 + kq*4];
        float4 a1 = *(float4*)&sA[(rr+16)*128 + kq*4];
        acc0.x = fmaf(a0.x,w0q.x, fmaf(a0.y,w1q.x, fmaf(a0.z,w2q.x, fmaf(a0.w,w3q.x, acc0.x))));
        acc0.y = fmaf(a0.x,w0q.y, fmaf(a0.y,w1q.y, fmaf(a0.z,w2q.y, fmaf(a0.w,w3q.y, acc0.y))));
        acc0.z = fmaf(a0.x,w0q.z, fmaf(a0.y,w1q.z, fmaf(a0.z,w2q.z, fmaf(a0.w,w3q.z, acc0.z))));
        acc0.w = fmaf(a0.x,w0q.w, fmaf(a0.y,w1q.w, fmaf(a0.z,w2q.w, fmaf(a0.w,w3q.w, acc0.w))));
        acc1.x = fmaf(a1.x,w0q.x, fmaf(a1.y,w1q.x, fmaf(a1.z,w2q.x, fmaf(a1.w,w3q.x, acc1.x))));
        acc1.y = fmaf(a1.x,w0q.y, fmaf(a1.y,w1q.y, fmaf(a1.z,w2q.y, fmaf(a1.w,w3q.y, acc1.y))));
        acc1.z = fmaf(a1.x,w0q.z, fmaf(a1.y,w1q.z, fmaf(a1.z,w2q.z, fmaf(a1.w,w3q.z, acc1.z))));
        acc1.w = fmaf(a1.x,w0q.w, fmaf(a1.y,w1q.w, fmaf(a1.z,w2q.w, fmaf(a1.w,w3q.w, acc1.w))));
    }
    const int col0 = cb*64 + cq*4;
    float b0=bias[col0], b1=bias[col0+1], b2=bias[col0+2], b3=bias[col0+3];
    int r0 = rt*32 + rr;
    *(float4*)&out[(size_t)r0*DIM + col0]      = make_float4(acc0.x+b0, acc0.y+b1, acc0.z+b2, acc0.w+b3);
    *(float4*)&out[(size_t)(r0+16)*DIM + col0] = make_float4(acc1.x+b0, acc1.y+b1, acc1.z+b2, acc1.w+b3);
}

// ------------- GAT GEMM: Wh = h @ W, fused e1/e2 64-col partial dots ---------------
__global__ __launch_bounds__(256) void gatgemm_k(const float* __restrict__ A,
    const float* __restrict__ W, const float* __restrict__ a1, const float* __restrict__ a2,
    float* __restrict__ out, float* __restrict__ e1p, float* __restrict__ e2p)
{
    __shared__ __align__(16) float sW[128*64];
    __shared__ __align__(16) float sA[32*128];
    const int rt = blockIdx.x, cb = blockIdx.y, tid = threadIdx.x;

    for (int e = tid; e < 128*64; e += 256){
        int k = e >> 6, cc = e & 63;
        sW[e] = W[k*DIM + cb*64 + cc];
    }
    const float4* Ab = (const float4*)(A + (size_t)rt*32*128);
    float4* sA4 = (float4*)sA;
    for (int q = tid; q < 32*32; q += 256) sA4[q] = Ab[q];
    __syncthreads();

    const int cq = tid & 15, rr = tid >> 4;
    float4 acc0 = make_float4(0.f,0.f,0.f,0.f);
    float4 acc1 = make_float4(0.f,0.f,0.f,0.f);
    for (int kq = 0; kq < 32; ++kq){
        float4 w0q = *(float4*)&sW[(kq*4+0)*64 + cq*4];
        float4 w1q = *(float4*)&sW[(kq*4+1)*64 + cq*4];
        float4 w2q = *(float4*)&sW[(kq*4+2)*64 + cq*4];
        float4 w3q = *(float4*)&sW[(kq*4+3)*64 + cq*4];
        float4 a0 = *(float4*)&sA[rr*128 + kq*4];
        float4 a1q = *(float4*)&sA[(rr+16)*128 + kq*4];
        acc0.x = fmaf(a0.x,w0q.x, fmaf(a0.y,w1q.x, fmaf(a0.z,w2q.x, fmaf(a0.w,w3q.x, acc0.x))));
        acc0.y = fmaf(a0.x,w0q.y, fmaf(a0.y,w1q.y, fmaf(a0.z,w2q.y, fmaf(a0.w,w3q.y, acc0.y))));
        acc0.z = fmaf(a0.x,w0q.z, fmaf(a0.y,w1q.z, fmaf(a0.z,w2q.z, fmaf(a0.w,w3q.z, acc0.z))));
        acc0.w = fmaf(a0.x,w0q.w, fmaf(a0.y,w1q.w, fmaf(a0.z,w2q.w, fmaf(a0.w,w3q.w, acc0.w))));
        acc1.x = fmaf(a1q.x,w0q.x, fmaf(a1q.y,w1q.x, fmaf(a1q.z,w2q.x, fmaf(a1q.w,w3q.x, acc1.x))));
        acc1.y = fmaf(a1q.x,w0q.y, fmaf(a1q.y,w1q.y, fmaf(a1q.z,w2q.y, fmaf(a1q.w,w3q.y, acc1.y))));
        acc1.z = fmaf(a1q.x,w0q.z, fmaf(a1q.y,w1q.z, fmaf(a1q.z,w2q.z, fmaf(a1q.w,w3q.z, acc1.z))));
        acc1.w = fmaf(a1q.x,w0q.w, fmaf(a1q.y,w1q.w, fmaf(a1q.z,w2q.w, fmaf(a1q.w,w3q.w, acc1.w))));
    }
    const int col0 = cb*64 + cq*4;
    int r0 = rt*32 + rr;
    *(float4*)&out[(size_t)r0*DIM + col0]      = acc0;
    *(float4*)&out[(size_t)(r0+16)*DIM + col0] = acc1;

    float a1v0=a1[col0], a1v1=a1[col0+1], a1v2=a1[col0+2], a1v3=a1[col0+3];
    float a2v0=a2[col0], a2v1=a2[col0+1], a2v2=a2[col0+2], a2v3=a2[col0+3];
    float p1r0 = acc0.x*a1v0 + acc0.y*a1v1 + acc0.z*a1v2 + acc0.w*a1v3;
    float p2r0 = acc0.x*a2v0 + acc0.y*a2v1 + acc0.z*a2v2 + acc0.w*a2v3;
    float p1r1 = acc1.x*a1v0 + acc1.y*a1v1 + acc1.z*a1v2 + acc1.w*a1v3;
    float p2r1 = acc1.x*a2v0 + acc1.y*a2v1 + acc1.z*a2v2 + acc1.w*a2v3;
    #pragma unroll
    for (int msk = 1; msk < 16; msk <<= 1){
        p1r0 += __shfl_xor(p1r0, msk); p2r0 += __shfl_xor(p2r0, msk);
        p1r1 += __shfl_xor(p1r1, msk); p2r1 += __shfl_xor(p2r1, msk);
    }
    if (cq == 0){
        e1p[cb*BN + r0]    = p1r0;  e2p[cb*BN + r0]    = p2r0;
        e1p[cb*BN + r0+16] = p1r1;  e2p[cb*BN + r0+16] = p2r1;
    }
}

// ------------- final projection GEMM, output dtype per flag ------------------------
__global__ __launch_bounds__(256) void gemmout_k(const float* __restrict__ A,
    const float* __restrict__ W, const float* __restrict__ bias,
    void* __restrict__ outp, const float* __restrict__ flag)
{
    __shared__ __align__(16) float sW[128*64];
    __shared__ __align__(16) float sA[32*128];
    const int rt = blockIdx.x, tid = threadIdx.x;
    for (int e = tid; e < 128*64; e += 256){
        int k = e >> 6, cc = e & 63;
        sW[e] = W[k*ODIM + cc];
    }
    const float4* Ab = (const float4*)(A + (size_t)rt*32*128);
    float4* sA4 = (float4*)sA;
    for (int q = tid; q < 32*32; q += 256) sA4[q] = Ab[q];
    __syncthreads();

    const int cq = tid & 15, rr = tid >> 4;
    float4 acc0 = make_float4(0.f,0.f,0.f,0.f);
    float4 acc1 = make_float4(0.f,0.f,0.f,0.f);
    for (int kq = 0; kq < 32; ++kq){
        float4 w0q = *(float4*)&sW[(kq*4+0)*64 + cq*4];
        float4 w1q = *(float4*)&sW[(kq*4+1)*64 + cq*4];
        float4 w2q = *(float4*)&sW[(kq*4+2)*64 + cq*4];
        float4 w3q = *(float4*)&sW[(kq*4+3)*64 + cq*4];
        float4 a0 = *(float4*)&sA[rr*128 + kq*4];
        float4 a1 = *(float4*)&sA[(rr+16)*128 + kq*4];
        acc0.x = fmaf(a0.x,w0q.x, fmaf(a0.y,w1q.x, fmaf(a0.z,w2q.x, fmaf(a0.w,w3q.x, acc0.x))));
        acc0.y = fmaf(a0.x,w0q.y, fmaf(a0.y,w1q.y, fmaf(a0.z,w2q.y, fmaf(a0.w,w3q.y, acc0.y))));
        acc0.z = fmaf(a0.x,w0q.z, fmaf(a0.y,w1q.z, fmaf(a0.z,w2q.z, fmaf(a0.w,w3q.z, acc0.z))));
        acc0.w = fmaf(a0.x,w0q.w, fmaf(a0.y,w1q.w, fmaf(a0.z,w2q.w, fmaf(a0.w,w3q.w, acc0.w))));
        acc1.x = fmaf(a1.x,w0q.x, fmaf(a1.y,w1q.x, fmaf(a1.z,w2q.x, fmaf(a1.w,w3q.x, acc1.x))));
        acc1.y = fmaf(a1.x,w0q.y, fmaf(a1.y,w1q.y, fmaf(a1.z,w2q.y, fmaf(a1.w,w3q.y, acc1.y))));
        acc1.z = fmaf(a1.x,w0q.z, fmaf(a1.y,w1q.z, fmaf(a1.z,w2q.z, fmaf(a1.w,w3q.z, acc1.z))));
        acc1.w = fmaf(a1.x,w0q.w, fmaf(a1.y,w1q.w, fmaf(a1.z,w2q.w, fmaf(a1.w,w3q.w, acc1.w))));
    }
    const int col0 = cq*4;
    float b0=bias[col0], b1=bias[col0+1], b2=bias[col0+2], b3=bias[col0+3];
    float o0[4] = {acc0.x+b0, acc0.y+b1, acc0.z+b2, acc0.w+b3};
    float o1[4] = {acc1.x+b0, acc1.y+b1, acc1.z+b2, acc1.w+b3};
    int r0 = rt*32 + rr;
    size_t p0 = (size_t)r0*ODIM + col0, p1 = (size_t)(r0+16)*ODIM + col0;
    if (flag[0] != 0.0f){
        bf16* ob = (bf16*)outp;
        #pragma unroll
        for (int i = 0; i < 4; ++i){ ob[p0+i] = __float2bfloat16(o0[i]); ob[p1+i] = __float2bfloat16(o1[i]); }
    } else {
        float* of = (float*)outp;
        *(float4*)&of[p0] = make_float4(o0[0],o0[1],o0[2],o0[3]);
        *(float4*)&of[p1] = make_float4(o1[0],o1[1],o1[2],o1[3]);
    }
}

// ------------- per-batch bitonic sort of e2 (2000 -> pad 2048) --------------------
// Wave-local optimization: for stride <= 64, thread t's pair (i, i+stride) lies
// entirely in its wave's private 128-element window [128*(t>>6), 128*(t>>6)+128),
// so those stages need no __syncthreads (wave64 lockstep + in-order per-wave LDS);
// only a compiler reorder fence. Barriers: 66 -> 15.
#define WAVE_FENCE() __asm__ volatile("" ::: "memory")
__global__ void sort_k(const float* __restrict__ e2p, float* __restrict__ e2s, int* __restrict__ sidx,
                       float* __restrict__ wp, float* __restrict__ wn, float* __restrict__ e2m)
{
    __shared__ float v[2048];
    __shared__ int  ix[2048];
    const int b = blockIdx.x, t = threadIdx.x;   // 1024 threads
    for (int i = t; i < 2048; i += 1024){
        v[i]  = (i < NNODE) ? (e2p[b*NNODE + i] + e2p[BN + b*NNODE + i]) : 3.0e38f;
        ix[i] = i;
    }
    __syncthreads();

    // sizes 2..128: all strides <= 64 -> fully wave-local, no block barriers
    #pragma unroll 1
    for (int size = 2; size <= 128; size <<= 1){
        #pragma unroll 1
        for (int stride = size >> 1; stride > 0; stride >>= 1){
            int i = 2*t - (t & (stride-1));
            int j = i + stride;
            bool asc = ((i & size) == 0);
            float vi = v[i], vj = v[j];
            bool sw = asc ? (vi > vj) : (vi < vj);
            if (sw){ v[i]=vj; v[j]=vi; int tm=ix[i]; ix[i]=ix[j]; ix[j]=tm; }
            WAVE_FENCE();
        }
    }
    __syncthreads();

    // sizes 256..2048: strides >=128 need block barriers; strides <=64 wave-local
    #pragma unroll 1
    for (int size = 256; size <= 2048; size <<= 1){
        #pragma unroll 1
        for (int stride = size >> 1; stride >= 128; stride >>= 1){
            int i = 2*t - (t & (stride-1));
            int j = i + stride;
            bool asc = ((i & size) == 0);
            float vi = v[i], vj = v[j];
            bool sw = asc ? (vi > vj) : (vi < vj);
            if (sw){ v[i]=vj; v[j]=vi; int tm=ix[i]; ix[i]=ix[j]; ix[j]=tm; }
            __syncthreads();
        }
        #pragma unroll 1
        for (int stride = 64; stride > 0; stride >>= 1){
            int i = 2*t - (t & (stride-1));
            int j = i + stride;
            bool asc = ((i & size) == 0);
            float vi = v[i], vj = v[j];
            bool sw = asc ? (vi > vj) : (vi < vj);
            if (sw){ v[i]=vj; v[j]=vi; int tm=ix[i]; ix[i]=ix[j]; ix[j]=tm; }
            WAVE_FENCE();
        }
        __syncthreads();
    }

    float mx = v[NNODE-1];   // pads sort to 2000..2047, so this is the true max
    for (int i = t; i < NNODE; i += 1024){
        float val = v[i];
        e2s [b*NNODE+i] = val;
        sidx[b*NNODE+i] = ix[i];
        wp  [b*NNODE+i] = __expf(val - mx);          // <= 1
        wn  [b*NNODE+i] = __expf(0.2f*(val - mx));   // <= 1
    }
    if (t == 0) e2m[b] = mx;
}

// ------------- pass A: per-chunk partial sums (vector[D] + scalar) ----------------
__global__ void passA_k(const float* __restrict__ Wh, const int* __restrict__ sidx,
    const float* __restrict__ wp, const float* __restrict__ wn,
    float* __restrict__ chunkP, float* __restrict__ chunkN,
    float* __restrict__ schunkP, float* __restrict__ schunkN)
{
    const int b = blockIdx.x / CHK, c = blockIdx.x % CHK, d = threadIdx.x;
    const int base = b*NNODE;
    float sp=0.f, sn=0.f, ssp=0.f, ssn=0.f;
    #pragma unroll 4
    for (int r = c*CKS; r < c*CKS + CKS; ++r){
        int j = sidx[base + r];
        float whv = Wh[((size_t)base + j)*DIM + d];
        float wpv = wp[base + r], wnv = wn[base + r];
        sp = fmaf(wpv, whv, sp);  sn = fmaf(wnv, whv, sn);
        ssp += wpv;  ssn += wnv;
    }
    const int idx = b*CHK + c;
    chunkP[idx*DIM + d] = sp;
    chunkN[idx*DIM + d] = sn;
    if (d == 0){ schunkP[idx] = ssp; schunkN[idx] = ssn; }
}

// ------------- pass B: cross-chunk suffix (P) / prefix (N) offsets (exclusive) -----
__global__ __launch_bounds__(256) void passB_k(
    const float* __restrict__ chunkP, const float* __restrict__ chunkN,
    const float* __restrict__ schunkP, const float* __restrict__ schunkN,
    float* __restrict__ offP, float* __restrict__ offN,
    float* __restrict__ soffP, float* __restrict__ soffN)
{
    const int b = blockIdx.x, tid = threadIdx.x;
    const bool doP = (blockIdx.y == 0);
    const float* chunk  = doP ? chunkP  : chunkN;
    const float* schunk = doP ? schunkP : schunkN;
    float* off  = doP ? offP  : offN;
    float* soff = doP ? soffP : soffN;

    if (tid < 128){
        const int d = tid;
        float acc = 0.f, v[25];
        #pragma unroll
        for (int t = 0; t < 5; ++t){
            const int c0 = doP ? (4-t)*25 : t*25;
            #pragma unroll
            for (int k = 0; k < 25; ++k) v[k] = chunk[(b*CHK + c0 + k)*DIM + d];
            if (doP){
                #pragma unroll
                for (int k = 24; k >= 0; --k){ off[(b*CHK + c0 + k)*DIM + d] = acc; acc += v[k]; }
            } else {
                #pragma unroll
                for (int k = 0; k < 25; ++k){ off[(b*CHK + c0 + k)*DIM + d] = acc; acc += v[k]; }
            }
        }
    } else if (tid == 128){
        float sacc = 0.f, sv[25];
        #pragma unroll
        for (int t = 0; t < 5; ++t){
            const int c0 = doP ? (4-t)*25 : t*25;
            #pragma unroll
            for (int k = 0; k < 25; ++k) sv[k] = schunk[b*CHK + c0 + k];
            if (doP){
                #pragma unroll
                for (int k = 24; k >= 0; --k){ soff[b*CHK + c0 + k] = sacc; sacc += sv[k]; }
            } else {
                #pragma unroll
                for (int k = 0; k < 25; ++k){ soff[b*CHK + c0 + k] = sacc; sacc += sv[k]; }
            }
        }
    }
}

// ------------- pass C: full suffix (pos) / prefix (neg) arrays over sorted order ---
__global__ void passC_k(const float* __restrict__ Wh, const int* __restrict__ sidx,
    const float* __restrict__ wp, const float* __restrict__ wn,
    const float* __restrict__ offP, const float* __restrict__ offN,
    const float* __restrict__ soffP, const float* __restrict__ soffN,
    float* __restrict__ Ppos, float* __restrict__ Pneg,
    float* __restrict__ pposs, float* __restrict__ pnegs)
{
    const int b = blockIdx.x / CHK, c = blockIdx.x % CHK, d = threadIdx.x;
    const int base = b*NNODE;
    const size_t pb = (size_t)b*NP1;
    const int idx = b*CHK + c;
    const int r0 = c*CKS, r1 = r0 + CKS;

    if (c == CHK-1){
        Ppos[(pb + NNODE)*DIM + d] = 0.f;
        if (d == 0) pposs[pb + NNODE] = 0.f;
    }
    float pr = offP[idx*DIM + d], spr = soffP[idx];     // suffix sums, descending
    for (int r = r1-1; r >= r0; --r){
        int j = sidx[base + r];
        float whv = Wh[((size_t)base + j)*DIM + d];
        float wpv = wp[base + r];
        pr  = fmaf(wpv, whv, pr);
        spr += wpv;
        Ppos[(pb + r)*DIM + d] = pr;
        if (d == 0) pposs[pb + r] = spr;
    }
    float nr = offN[idx*DIM + d], snr = soffN[idx];     // prefix sums (exclusive)
    for (int r = r0; r < r1; ++r){
        int j = sidx[base + r];
        float whv = Wh[((size_t)base + j)*DIM + d];
        float wnv = wn[base + r];
        Pneg[(pb + r)*DIM + d] = nr;
        if (d == 0) pnegs[pb + r] = snr;
        nr  = fmaf(wnv, whv, nr);
        snr += wnv;
    }
    if (c == CHK-1){
        Pneg[(pb + NNODE)*DIM + d] = nr;
        if (d == 0) pnegs[pb + NNODE] = snr;
    }
}

// ------------- output, 16 rows per block: parallel binsearch then stream -----------
__global__ __launch_bounds__(128) void out16_k(const float* __restrict__ e1p,
    const float* __restrict__ e2s, const float* __restrict__ e2m,
    const float* __restrict__ Ppos, const float* __restrict__ Pneg,
    const float* __restrict__ pposs, const float* __restrict__ pnegs, float* __restrict__ h)
{
    __shared__ int   slo[CKS];
    __shared__ float sps[CKS], sns[CKS];
    const int b = blockIdx.x / CHK, c = blockIdx.x % CHK, d = threadIdx.x;
    const int base = b*NNODE, r0 = c*CKS;
    const size_t pb = (size_t)b*NP1;

    if (d < CKS){
        int row = base + r0 + d;
        float e1v = e1p[row] + e1p[BN + row];
        float s = e1v + e2m[b];
        float m = (s >= 0.f) ? s : 0.2f*s;
        sps[d] = __expf(s - m);
        sns[d] = __expf(0.2f*s - m);
        const float* es = e2s + base;
        float t = -e1v;
        int lo = 0, hi = NNODE;
        while (lo < hi){ int mid = (lo+hi) >> 1; if (es[mid] < t) lo = mid+1; else hi = mid; }
        slo[d] = lo;
    }
    __syncthreads();
    #pragma unroll 4
    for (int k = 0; k < CKS; ++k){
        int row = base + r0 + k;
        size_t kb = pb + slo[k];
        float numer = sps[k]*Ppos[kb*DIM + d] + sns[k]*Pneg[kb*DIM + d];
        float Z     = sps[k]*pposs[kb]        + sns[k]*pnegs[kb];
        float q = numer / Z;
        h[(size_t)row*DIM + d] = (q > 0.f) ? q : ((q == q) ? 0.f : q);
    }
}

extern "C" void kernel_launch(void* const* d_in, const int* in_sizes, int n_in,
                              void* d_out, int out_size, void* d_ws, size_t ws_size,
                              hipStream_t stream)
{
    (void)in_sizes; (void)n_in; (void)out_size; (void)ws_size;

    float* f = (float*)d_ws;
    float* flag    = f;  f += 4;
    float* cvt     = f;  f += CVT_TOT;                 // 0.56 MB
    float* h       = f;  f += (size_t)BN*DIM;          // 16.4 MB
    float* Wh      = f;  f += (size_t)BN*DIM;          // 16.4 MB
    float* Ppos    = f;  f += (size_t)BATCH*NP1*DIM;   // 16.4 MB
    float* Pneg    = f;  f += (size_t)BATCH*NP1*DIM;   // 16.4 MB
    float* chunkP  = f;  f += BATCH*CHK*DIM;           // 1 MB
    float* chunkN  = f;  f += BATCH*CHK*DIM;           // 1 MB
    float* offP    = f;  f += BATCH*CHK*DIM;           // 1 MB
    float* offN    = f;  f += BATCH*CHK*DIM;           // 1 MB
    float* schunkP = f;  f += BATCH*CHK;
    float* schunkN = f;  f += BATCH*CHK;
    float* soffP   = f;  f += BATCH*CHK;
    float* soffN   = f;  f += BATCH*CHK;
    float* e1p     = f;  f += 2*BN;                    // two 64-col partials
    float* e2p     = f;  f += 2*BN;
    float* e2s     = f;  f += BN;
    float* wp      = f;  f += BN;
    float* wn      = f;  f += BN;
    float* pposs   = f;  f += BATCH*NP1;
    float* pnegs   = f;  f += BATCH*NP1;
    float* e2m     = f;  f += 16;
    int*   sidx    = (int*)f;

    // 1. convert all inputs to fp32 (sniff embedded)
    InPtrs ip;
    for (int i = 0; i < 10; ++i) ip.p[i] = d_in[i];
    convert_all_k<<<(CVT_TOT+255)/256, 256, 0, stream>>>(ip, cvt, flag);

    // 2. fused encoder (enc0 + gemm)
    encgemm_k<<<dim3(BN/32, 2), 256, 0, stream>>>(cvt, h);

    // 3. GAT layers (exact separable-softmax factorization)
    for (int l = 0; l < NLAYER; ++l){
        gatgemm_k<<<dim3(BN/32, 2), 256, 0, stream>>>(h, cvt + OFF_GW + l*DIM*DIM,
                                                      cvt + OFF_GA1 + l*DIM, cvt + OFF_GA2 + l*DIM,
                                                      Wh, e1p, e2p);
        sort_k<<<BATCH, 1024, 0, stream>>>(e2p, e2s, sidx, wp, wn, e2m);
        passA_k<<<BATCH*CHK, DIM, 0, stream>>>(Wh, sidx, wp, wn, chunkP, chunkN, schunkP, schunkN);
        passB_k<<<dim3(BATCH, 2), 256, 0, stream>>>(chunkP, chunkN, schunkP, schunkN,
                                                    offP, offN, soffP, soffN);
        passC_k<<<BATCH*CHK, DIM, 0, stream>>>(Wh, sidx, wp, wn, offP, offN, soffP, soffN,
                                               Ppos, Pneg, pposs, pnegs);
        out16_k<<<BATCH*CHK, DIM, 0, stream>>>(e1p, e2s, e2m, Ppos, Pneg, pposs, pnegs, h);
    }

    // 4. projection, output dtype per flag
    gemmout_k<<<BN/32, 256, 0, stream>>>(h, cvt + OFF_PW, cvt + OFF_PB, d_out, flag);
}